// Round 3
// baseline (451.049 us; speedup 1.0000x reference)
//
#include <hip/hip_runtime.h>
#include <cfloat>

#define NROWS 131072
#define DIM 256
#define KCODES 512
#define DECAYF 0.99f
#define OMDECAYF 0.01f
#define EPSF 1e-5f
#define BATCHF 32.0f

#define CHUNK 128
#define ROWMASK 0x1FFFF
#define GBLOCKS 1024

// ---- MFMA argmin geometry ----
#define RT 2                  // row-tiles (16 rows each) per wave
#define BMW (RT * 16)         // 32 rows per wave
#define BMB (4 * BMW)         // 128 rows per block (4 waves)
#define PLANE_STRIDE (KCODES * DIM)   // halves per cb plane (131072 = 256 KB)
#define NTILE (KCODES / 16)   // 32 code-tiles of 16

typedef __attribute__((ext_vector_type(8))) _Float16 half8;  // 8 f16 = 4 VGPR
typedef __attribute__((ext_vector_type(4))) float f32x4;

// ---------------- ws layout (bytes) ----------------
// 0      : cnorm       512 f
// 2048   : counts      512 i   (memset 0 each launch)
// 6144   : cursor      512 i   (written by scan)
// 8192   : loss_part   1024 f  (written by gather, reduced in scan)
// 12288  : enc_int     131072 i
// 536576 : rowlist     131072 i  (packed (code<<17)|row, sorted by code)
// fp16 codebook planes (512 KB, FRAGMENT-ORDERED) live in the out_code region
// of d_out: written by cnorm_kernel, consumed by argmin_kernel, then
// overwritten by gather (stream-ordered, safe).

// cnorm + init e_new with decay*e_i + emit 2-way fp16 split planes of cb in
// MFMA B-FRAGMENT ORDER: plane[((tile16*8 + kc)*64 + lane)*8 + j] where for
// code k, dim t: tile16=k>>4, lane=((t>>3)&3)*16 + (k&15), kc=t>>5, j=t&7.
// This is exactly the per-lane layout mfma_f32_16x16x32_f16 wants for B
// (lane&15 = code col, k = (lane>>4)*8 + j) -> argmin loads B straight from
// global, coalesced 1KB per wave instruction, no LDS staging at all.
__global__ __launch_bounds__(256) void cnorm_kernel(const float* __restrict__ cb,
                                                    const float* __restrict__ e_i,
                                                    float* __restrict__ cnorm,
                                                    float* __restrict__ en_out,
                                                    unsigned short* __restrict__ planes) {
  int k = blockIdx.x;
  int t = threadIdx.x;
  size_t idx = (size_t)k * DIM + t;
  float v = cb[idx];
  en_out[idx] = DECAYF * e_i[idx];
  _Float16 h = (_Float16)v;           // RNE
  float r1 = v - (float)h;            // exact
  _Float16 m = (_Float16)r1;          // RNE
  unsigned short hb, mb;
  __builtin_memcpy(&hb, &h, 2);
  __builtin_memcpy(&mb, &m, 2);
  int tile = k >> 4, cl = k & 15;
  int kc = t >> 5, lk = (t >> 3) & 3, j = t & 7;
  size_t faddr = ((size_t)((tile * 8 + kc) * 64 + lk * 16 + cl)) * 8 + j;
  planes[faddr] = hb;                   // plane h
  planes[PLANE_STRIDE + faddr] = mb;    // plane m
  float s = v * v;
  for (int off = 32; off > 0; off >>= 1) s += __shfl_down(s, off);
  __shared__ float p[4];
  if ((t & 63) == 0) p[t >> 6] = s;
  __syncthreads();
  if (t == 0) cnorm[k] = (p[0] + p[1]) + (p[2] + p[3]);
}

// MFMA distance-GEMM + argmin + histogram. BARRIER-FREE main loop.
// score = ||c||^2 - 2*dot (||z||^2 const per row). dot via 3 f16 MFMA
// products of 2-way splits: z=(a_h+a_m+r_z), c=(b_h+b_m+r_c); compute
// hh + mh + hm in f32 accumulate. Dropped terms (mm, residuals) ~2^-22
// relative -- same error order as round-2's passing version.
// Codebook B-fragments (512 KB) are L2-resident and loaded directly from
// global in fragment order -> no LDS pipe, no bank conflicts, no barriers;
// loads pipeline freely across tiles under counted vmcnt.
__global__ __launch_bounds__(256, 2) void argmin_kernel(
    const float* __restrict__ z, const unsigned short* __restrict__ planes,
    const float* __restrict__ cnorm, int* __restrict__ enc_int,
    float* __restrict__ enc_out, int* __restrict__ counts) {
  __shared__ float cn_s[KCODES];
  __shared__ int hist[KCODES];

  const int tid = threadIdx.x;
  const int w = tid >> 6;
  const int l = tid & 63;
  const int lc = l & 15;   // fragment row/col index
  const int lk = l >> 4;   // k-group (0..3)

  hist[tid] = 0;
  hist[tid + 256] = 0;
  cn_s[tid] = cnorm[tid];
  cn_s[tid + 256] = cnorm[tid + 256];

  // ---- load this wave's 32 z-rows into register fragments (2 fp16 splits) ----
  // A-frag layout for mfma_f32_16x16x32_f16: lane holds row (l&15),
  // k = (l>>4)*8 + j, j=0..7 contiguous.  128 VGPRs total.
  half8 a_h[RT][8], a_m[RT][8];
#pragma unroll
  for (int rt = 0; rt < RT; ++rt) {
    int row = blockIdx.x * BMB + w * BMW + rt * 16 + lc;
    const float* zr = z + (size_t)row * DIM;
#pragma unroll
    for (int ch = 0; ch < 8; ++ch) {
      float4 v0 = *(const float4*)&zr[ch * 32 + lk * 8];
      float4 v1 = *(const float4*)&zr[ch * 32 + lk * 8 + 4];
      float vv[8] = {v0.x, v0.y, v0.z, v0.w, v1.x, v1.y, v1.z, v1.w};
      half8 hh, mm;
#pragma unroll
      for (int j = 0; j < 8; ++j) {
        float f = vv[j];
        _Float16 hb = (_Float16)f;     // RNE
        float r1 = f - (float)hb;      // exact
        hh[j] = hb;
        mm[j] = (_Float16)r1;          // RNE
      }
      a_h[rt][ch] = hh; a_m[rt][ch] = mm;
    }
  }

  float minv[RT][4];
  int mini[RT][4];
#pragma unroll
  for (int rt = 0; rt < RT; ++rt)
#pragma unroll
    for (int q = 0; q < 4; ++q) { minv[rt][q] = FLT_MAX; mini[rt][q] = 0; }

  __syncthreads();  // cn_s / hist init visible (only block-wide barrier pre-epilogue)

  // per-lane fragment base pointers (lane offset folded in once)
  const half8* bb_h = (const half8*)planes + l;
  const half8* bb_m = (const half8*)(planes + (size_t)PLANE_STRIDE) + l;

#pragma unroll 2
  for (int T = 0; T < NTILE; ++T) {
    f32x4 acc0 = {0.f, 0.f, 0.f, 0.f};
    f32x4 acc1 = {0.f, 0.f, 0.f, 0.f};
#pragma unroll
    for (int kc = 0; kc < 8; ++kc) {
      int fi = (T * 8 + kc) * 64;
      half8 bh = bb_h[fi];
      half8 bm = bb_m[fi];
      acc0 = __builtin_amdgcn_mfma_f32_16x16x32_f16(a_h[0][kc], bh, acc0, 0, 0, 0);
      acc1 = __builtin_amdgcn_mfma_f32_16x16x32_f16(a_h[1][kc], bh, acc1, 0, 0, 0);
      acc0 = __builtin_amdgcn_mfma_f32_16x16x32_f16(a_m[0][kc], bh, acc0, 0, 0, 0);
      acc1 = __builtin_amdgcn_mfma_f32_16x16x32_f16(a_m[1][kc], bh, acc1, 0, 0, 0);
      acc0 = __builtin_amdgcn_mfma_f32_16x16x32_f16(a_h[0][kc], bm, acc0, 0, 0, 0);
      acc1 = __builtin_amdgcn_mfma_f32_16x16x32_f16(a_h[1][kc], bm, acc1, 0, 0, 0);
    }
    // C layout: col = lane&15 (code), row = (lane>>4)*4 + q
    int code = T * 16 + lc;
    float cn = cn_s[code];
#pragma unroll
    for (int q = 0; q < 4; ++q) {
      float s0 = cn - 2.f * acc0[q];
      if (s0 < minv[0][q]) { minv[0][q] = s0; mini[0][q] = code; }
      float s1 = cn - 2.f * acc1[q];
      if (s1 < minv[1][q]) { minv[1][q] = s1; mini[1][q] = code; }
    }
  }

  // ---- cross-lane argmin over the 16 code-lanes of each row group ----
#pragma unroll
  for (int rt = 0; rt < RT; ++rt) {
#pragma unroll
    for (int q = 0; q < 4; ++q) {
      float v = minv[rt][q];
      int idx = mini[rt][q];
      for (int off = 1; off < 16; off <<= 1) {
        float ov = __shfl_xor(v, off);
        int oi = __shfl_xor(idx, off);
        if (ov < v || (ov == v && oi < idx)) { v = ov; idx = oi; }  // first-min wins
      }
      if (lc == 0) {
        int row = blockIdx.x * BMB + w * BMW + rt * 16 + lk * 4 + q;
        enc_int[row] = idx;
        enc_out[row] = (float)idx;
        atomicAdd(&hist[idx], 1);
      }
    }
  }
  __syncthreads();
  atomicAdd(&counts[tid], hist[tid]);
  atomicAdd(&counts[tid + 256], hist[tid + 256]);
}

// code gather -> code_ste output, per-block loss partials (NO same-address atomics)
__global__ __launch_bounds__(256) void gather_kernel(
    const float* __restrict__ z, const float* __restrict__ cb,
    const int* __restrict__ enc, float* __restrict__ code_out,
    float* __restrict__ loss_part) {
  const int per_block = (NROWS * (DIM / 4)) / GBLOCKS;  // 8192 float4s
  int base = blockIdx.x * per_block;
  float s = 0.f;
  for (int it = 0; it < per_block; it += 256) {
    int e4 = base + it + threadIdx.x;
    int row = e4 >> 6;        // 64 float4 per row
    int d4 = (e4 & 63) << 2;
    int k = enc[row];
    float4 zv = *(const float4*)&z[(size_t)e4 * 4];
    float4 cv = *(const float4*)&cb[(size_t)k * DIM + d4];
    *(float4*)&code_out[(size_t)e4 * 4] = cv;
    float dx = zv.x - cv.x, dy = zv.y - cv.y, dz = zv.z - cv.z, dw = zv.w - cv.w;
    s += dx * dx + dy * dy + dz * dz + dw * dw;
  }
  for (int off = 32; off > 0; off >>= 1) s += __shfl_down(s, off);
  __shared__ float p[4];
  int t = threadIdx.x;
  if ((t & 63) == 0) p[t >> 6] = s;
  __syncthreads();
  if (t == 0) loss_part[blockIdx.x] = (p[0] + p[1]) + (p[2] + p[3]);
}

// single block: n_new + exclusive prefix sum of counts -> cursor; loss reduce
__global__ __launch_bounds__(512) void scan_kernel(
    const int* __restrict__ counts, const float* __restrict__ n_i,
    float* __restrict__ n_new_out, int* __restrict__ cursor,
    const float* __restrict__ loss_part, float* __restrict__ loss_out) {
  __shared__ int sd[KCODES];
  int t = threadIdx.x;
  int c = counts[t];
  float nn = DECAYF * n_i[t] + OMDECAYF * (float)c;
  nn = (nn + EPSF) / (BATCHF + (float)KCODES * EPSF) * BATCHF;
  n_new_out[t] = nn;
  sd[t] = c;
  __syncthreads();
  for (int off = 1; off < KCODES; off <<= 1) {
    int v = (t >= off) ? sd[t - off] : 0;
    __syncthreads();
    sd[t] += v;
    __syncthreads();
  }
  cursor[t] = sd[t] - c;
  // loss reduction: 1024 partials over 512 threads
  float ls = loss_part[t] + loss_part[t + 512];
  for (int off = 32; off > 0; off >>= 1) ls += __shfl_down(ls, off);
  __shared__ float lp[8];
  if ((t & 63) == 0) lp[t >> 6] = ls;
  __syncthreads();
  if (t == 0) {
    float tot = 0.f;
#pragma unroll
    for (int i = 0; i < 8; ++i) tot += lp[i];
    loss_out[0] = 0.25f * tot / 33554432.0f;
  }
}

// LDS-aggregated counting-sort scatter: writes packed (code<<17)|row.
__global__ __launch_bounds__(256) void scatter_kernel(
    const int* __restrict__ enc, int* __restrict__ cursor,
    int* __restrict__ rowlist) {
  __shared__ int lcnt[KCODES];
  __shared__ int lbase[KCODES];
  int tid = threadIdx.x;
  int row = blockIdx.x * 256 + tid;
  lcnt[tid] = 0;
  lcnt[tid + 256] = 0;
  __syncthreads();
  int k = enc[row];
  int p = atomicAdd(&lcnt[k], 1);
  __syncthreads();
  int c0 = lcnt[tid];
  if (c0) lbase[tid] = atomicAdd(&cursor[tid], c0);
  int c1 = lcnt[tid + 256];
  if (c1) lbase[tid + 256] = atomicAdd(&cursor[tid + 256], c1);
  __syncthreads();
  rowlist[lbase[k] + p] = (k << 17) | row;
}

// Load-balanced segmented sum over sorted rowlist: 128 rows per block,
// run-length accumulate in registers, one atomicAdd per run per dim.
__global__ __launch_bounds__(256) void chunk_sum_kernel(
    const float* __restrict__ z, const int* __restrict__ rowlist,
    float* __restrict__ en_out) {
  __shared__ int rl[CHUNK];
  int tid = threadIdx.x;
  int d = tid;
  if (tid < CHUNK) rl[tid] = rowlist[blockIdx.x * CHUNK + tid];
  __syncthreads();
  int cur = rl[0] >> 17;
  float s = 0.f;
  for (int i = 0; i < CHUNK; i += 4) {
    int p0 = rl[i + 0], p1 = rl[i + 1], p2 = rl[i + 2], p3 = rl[i + 3];
    float v0 = z[(size_t)(p0 & ROWMASK) * DIM + d];
    float v1 = z[(size_t)(p1 & ROWMASK) * DIM + d];
    float v2 = z[(size_t)(p2 & ROWMASK) * DIM + d];
    float v3 = z[(size_t)(p3 & ROWMASK) * DIM + d];
    int k;
    k = p0 >> 17;
    if (k != cur) { atomicAdd(&en_out[(size_t)cur * DIM + d], OMDECAYF * s); s = 0.f; cur = k; }
    s += v0;
    k = p1 >> 17;
    if (k != cur) { atomicAdd(&en_out[(size_t)cur * DIM + d], OMDECAYF * s); s = 0.f; cur = k; }
    s += v1;
    k = p2 >> 17;
    if (k != cur) { atomicAdd(&en_out[(size_t)cur * DIM + d], OMDECAYF * s); s = 0.f; cur = k; }
    s += v2;
    k = p3 >> 17;
    if (k != cur) { atomicAdd(&en_out[(size_t)cur * DIM + d], OMDECAYF * s); s = 0.f; cur = k; }
    s += v3;
  }
  atomicAdd(&en_out[(size_t)cur * DIM + d], OMDECAYF * s);
}

// cbn = e_new / n_new
__global__ __launch_bounds__(256) void finalize_kernel(
    const float* __restrict__ en, const float* __restrict__ n_new,
    float* __restrict__ cbn_out) {
  int k = blockIdx.x;
  int d = threadIdx.x;
  size_t idx = (size_t)k * DIM + d;
  cbn_out[idx] = en[idx] / n_new[k];
}

extern "C" void kernel_launch(void* const* d_in, const int* in_sizes, int n_in,
                              void* d_out, int out_size, void* d_ws, size_t ws_size,
                              hipStream_t stream) {
  const float* z = (const float*)d_in[0];
  const float* cb = (const float*)d_in[1];
  const float* n_i = (const float*)d_in[2];
  const float* e_i = (const float*)d_in[3];

  float* out = (float*)d_out;
  float* out_code = out;                    // 33554432
  float* out_loss = out + 33554432;         // 1
  float* out_enc = out + 33554433;          // 131072
  float* out_cbn = out + 33685505;          // 131072
  float* out_nn = out + 33816577;           // 512
  float* out_en = out + 33817089;           // 131072

  char* ws = (char*)d_ws;
  float* cnorm = (float*)(ws + 0);
  int* counts = (int*)(ws + 2048);
  int* cursor = (int*)(ws + 6144);
  float* loss_part = (float*)(ws + 8192);
  int* enc_int = (int*)(ws + 12288);
  int* rowlist = (int*)(ws + 536576);

  // fp16 split planes of the codebook (fragment-ordered): scratch inside
  // out_code (512 KB), consumed by argmin before gather overwrites the region.
  unsigned short* planes = (unsigned short*)out_code;

  // zero counts (ws is poisoned 0xAA before each launch)
  hipMemsetAsync(ws + 2048, 0, 2048, stream);

  cnorm_kernel<<<KCODES, 256, 0, stream>>>(cb, e_i, cnorm, out_en, planes);
  argmin_kernel<<<NROWS / BMB, 256, 0, stream>>>(z, planes, cnorm, enc_int, out_enc, counts);
  gather_kernel<<<GBLOCKS, 256, 0, stream>>>(z, cb, enc_int, out_code, loss_part);
  scan_kernel<<<1, KCODES, 0, stream>>>(counts, n_i, out_nn, cursor, loss_part, out_loss);
  scatter_kernel<<<NROWS / 256, 256, 0, stream>>>(enc_int, cursor, rowlist);
  chunk_sum_kernel<<<NROWS / CHUNK, 256, 0, stream>>>(z, rowlist, out_en);
  finalize_kernel<<<KCODES, 256, 0, stream>>>(out_en, out_nn, out_cbn);
}

// Round 4
// 395.990 us; speedup vs baseline: 1.1390x; 1.1390x over previous
//
#include <hip/hip_runtime.h>
#include <cfloat>

#define NROWS 131072
#define DIM 256
#define KCODES 512
#define DECAYF 0.99f
#define OMDECAYF 0.01f
#define EPSF 1e-5f
#define BATCHF 32.0f

#define CHUNK 128
#define ROWMASK 0x1FFFF
#define GBLOCKS 1024

// ---- MFMA argmin geometry ----
#define RT 2                  // row-tiles (16 rows each) per wave
#define BMW (RT * 16)         // 32 rows per wave
#define BMB (4 * BMW)         // 128 rows per block (4 waves)
#define PLANE_STRIDE (KCODES * DIM)      // halves per cb plane (262144 B)
#define PLANE_BYTES (PLANE_STRIDE * 2)   // 262144
#define PC2 32                // codes per piece (2 tiles of 16)
#define NPIECE (KCODES / PC2) // 16
#define PIECE_H_BYTES 16384   // one plane's bytes per piece
#define SBUF_HALF 32768       // LDS bytes per buffer (both planes)

typedef __attribute__((ext_vector_type(8))) _Float16 half8;  // 8 f16 = 4 VGPR
typedef __attribute__((ext_vector_type(4))) float f32x4;

// ---------------- ws layout (bytes) ----------------
// 0      : cnorm       512 f
// 2048   : counts      512 i   (memset 0 each launch)
// 6144   : cursor      512 i   (written by scan)
// 8192   : loss_part   1024 f  (written by gather, reduced in scan)
// 12288  : enc_int     131072 i
// 536576 : rowlist     131072 i  (packed (code<<17)|row, sorted by code)
// fp16 codebook planes (512 KB, FRAGMENT-ORDERED) live in the out_code region
// of d_out: written by cnorm_kernel, consumed by argmin_kernel, then
// overwritten by gather (stream-ordered, safe).

// async global->LDS, 16B per lane (dest = wave-uniform base + lane*16)
__device__ __forceinline__ void gload_lds16(const void* g, void* l) {
  __builtin_amdgcn_global_load_lds(
      (const __attribute__((address_space(1))) unsigned int*)g,
      (__attribute__((address_space(3))) unsigned int*)l, 16, 0, 0);
}

// cnorm + init e_new with decay*e_i + emit 2-way fp16 split planes of cb in
// MFMA B-FRAGMENT ORDER: plane[((tile16*8 + kc)*64 + lane)*8 + j] where for
// code k, dim t: tile16=k>>4, lane=((t>>3)&3)*16 + (k&15), kc=t>>5, j=t&7.
// (exact per-lane layout mfma_f32_16x16x32_f16 wants for B). The LDS image in
// argmin is then a LINEAR copy -> global_load_lds constraint satisfied and
// ds_read_b128 fragment reads are the canonical contiguous pattern.
__global__ __launch_bounds__(256) void cnorm_kernel(const float* __restrict__ cb,
                                                    const float* __restrict__ e_i,
                                                    float* __restrict__ cnorm,
                                                    float* __restrict__ en_out,
                                                    unsigned short* __restrict__ planes) {
  int k = blockIdx.x;
  int t = threadIdx.x;
  size_t idx = (size_t)k * DIM + t;
  float v = cb[idx];
  en_out[idx] = DECAYF * e_i[idx];
  _Float16 h = (_Float16)v;           // RNE
  float r1 = v - (float)h;            // exact
  _Float16 m = (_Float16)r1;          // RNE
  unsigned short hb, mb;
  __builtin_memcpy(&hb, &h, 2);
  __builtin_memcpy(&mb, &m, 2);
  int tile = k >> 4, cl = k & 15;
  int kc = t >> 5, lk = (t >> 3) & 3, j = t & 7;
  size_t faddr = ((size_t)((tile * 8 + kc) * 64 + lk * 16 + cl)) * 8 + j;
  planes[faddr] = hb;                   // plane h
  planes[PLANE_STRIDE + faddr] = mb;    // plane m
  float s = v * v;
  for (int off = 32; off > 0; off >>= 1) s += __shfl_down(s, off);
  __shared__ float p[4];
  if ((t & 63) == 0) p[t >> 6] = s;
  __syncthreads();
  if (t == 0) cnorm[k] = (p[0] + p[1]) + (p[2] + p[3]);
}

// MFMA distance-GEMM + argmin + histogram, double-buffered LDS pipeline.
// score = ||c||^2 - 2*dot. dot via 3 f16 MFMA products of 2-way splits
// (hh + mh + hm; dropped terms ~2^-22 rel -- verified passing in r2/r3).
// Per piece (32 codes, both planes, 32 KB): stage NEXT piece via
// global_load_lds while computing current from LDS; one __syncthreads per
// piece (its implicit vmcnt/lgkm drain completes the dbuf handshake).
// 4 independent acc chains (2 code-tiles x 2 row-tiles) per kc step.
__global__ __launch_bounds__(256, 2) void argmin_kernel(
    const float* __restrict__ z, const unsigned short* __restrict__ planes,
    const float* __restrict__ cnorm, int* __restrict__ enc_int,
    float* __restrict__ enc_out, int* __restrict__ counts) {
  __shared__ __align__(16) unsigned char sbuf[2 * SBUF_HALF];  // 64 KiB
  __shared__ float cn_s[KCODES];
  __shared__ int hist[KCODES];

  const int tid = threadIdx.x;
  const int w = tid >> 6;
  const int l = tid & 63;
  const int lc = l & 15;   // fragment row/col index
  const int lk = l >> 4;   // k-group (0..3)

  hist[tid] = 0;
  hist[tid + 256] = 0;
  cn_s[tid] = cnorm[tid];
  cn_s[tid + 256] = cnorm[tid + 256];

  // ---- load this wave's 32 z-rows into register fragments (2 fp16 splits) ----
  half8 a_h[RT][8], a_m[RT][8];
#pragma unroll
  for (int rt = 0; rt < RT; ++rt) {
    int row = blockIdx.x * BMB + w * BMW + rt * 16 + lc;
    const float* zr = z + (size_t)row * DIM;
#pragma unroll
    for (int ch = 0; ch < 8; ++ch) {
      float4 v0 = *(const float4*)&zr[ch * 32 + lk * 8];
      float4 v1 = *(const float4*)&zr[ch * 32 + lk * 8 + 4];
      float vv[8] = {v0.x, v0.y, v0.z, v0.w, v1.x, v1.y, v1.z, v1.w};
      half8 hh, mm;
#pragma unroll
      for (int j = 0; j < 8; ++j) {
        float f = vv[j];
        _Float16 hb = (_Float16)f;     // RNE
        float r1 = f - (float)hb;      // exact
        hh[j] = hb;
        mm[j] = (_Float16)r1;          // RNE
      }
      a_h[rt][ch] = hh; a_m[rt][ch] = mm;
    }
  }

  float minv[RT][4];
  int mini[RT][4];
#pragma unroll
  for (int rt = 0; rt < RT; ++rt)
#pragma unroll
    for (int q = 0; q < 4; ++q) { minv[rt][q] = FLT_MAX; mini[rt][q] = 0; }

  const unsigned char* gplanes = (const unsigned char*)planes;

  // stage(piece p -> buffer b): 32 chunks of 1KB; wave w takes chunks w*8..w*8+7.
  // waves 0,1 -> h plane (chunks 0..15); waves 2,3 -> m plane (16..31): uniform.
  // LDS image: [h tile0 8K][h tile1 8K][m tile0 8K][m tile1 8K].
#define STAGE(p, b)                                                              \
  {                                                                              \
    const unsigned char* gh = gplanes + (size_t)(p) * PIECE_H_BYTES;             \
    unsigned char* lb = &sbuf[(b) * SBUF_HALF];                                  \
    _Pragma("unroll")                                                            \
    for (int q = 0; q < 8; ++q) {                                                \
      int c = w * 8 + q;                                                         \
      const unsigned char* g = (w < 2)                                           \
          ? gh + c * 1024 + l * 16                                               \
          : gh + PLANE_BYTES + (c - 16) * 1024 + l * 16;                         \
      gload_lds16(g, lb + c * 1024);                                             \
    }                                                                            \
  }

  // prologue: stage piece 0 into buffer 0
  STAGE(0, 0);
  __syncthreads();  // drains vmcnt (stage landed) + makes cn_s/hist visible

#pragma unroll 1
  for (int p = 0; p < NPIECE; ++p) {
    const int cur = p & 1;
    if (p + 1 < NPIECE) STAGE(p + 1, cur ^ 1);  // async, overlaps compute below

    const int lbase = cur * SBUF_HALF;
    f32x4 acc00 = {0.f, 0.f, 0.f, 0.f};  // tile0 x rowtile0
    f32x4 acc01 = {0.f, 0.f, 0.f, 0.f};  // tile0 x rowtile1
    f32x4 acc10 = {0.f, 0.f, 0.f, 0.f};  // tile1 x rowtile0
    f32x4 acc11 = {0.f, 0.f, 0.f, 0.f};  // tile1 x rowtile1
#pragma unroll
    for (int kc = 0; kc < 8; ++kc) {
      int o = lbase + kc * 1024 + l * 16;
      half8 bh0 = *(const half8*)&sbuf[o];
      half8 bh1 = *(const half8*)&sbuf[o + 8192];
      half8 bm0 = *(const half8*)&sbuf[o + 16384];
      half8 bm1 = *(const half8*)&sbuf[o + 24576];
      acc00 = __builtin_amdgcn_mfma_f32_16x16x32_f16(a_h[0][kc], bh0, acc00, 0, 0, 0);
      acc01 = __builtin_amdgcn_mfma_f32_16x16x32_f16(a_h[1][kc], bh0, acc01, 0, 0, 0);
      acc10 = __builtin_amdgcn_mfma_f32_16x16x32_f16(a_h[0][kc], bh1, acc10, 0, 0, 0);
      acc11 = __builtin_amdgcn_mfma_f32_16x16x32_f16(a_h[1][kc], bh1, acc11, 0, 0, 0);
      acc00 = __builtin_amdgcn_mfma_f32_16x16x32_f16(a_m[0][kc], bh0, acc00, 0, 0, 0);
      acc01 = __builtin_amdgcn_mfma_f32_16x16x32_f16(a_m[1][kc], bh0, acc01, 0, 0, 0);
      acc10 = __builtin_amdgcn_mfma_f32_16x16x32_f16(a_m[0][kc], bh1, acc10, 0, 0, 0);
      acc11 = __builtin_amdgcn_mfma_f32_16x16x32_f16(a_m[1][kc], bh1, acc11, 0, 0, 0);
      acc00 = __builtin_amdgcn_mfma_f32_16x16x32_f16(a_h[0][kc], bm0, acc00, 0, 0, 0);
      acc01 = __builtin_amdgcn_mfma_f32_16x16x32_f16(a_h[1][kc], bm0, acc01, 0, 0, 0);
      acc10 = __builtin_amdgcn_mfma_f32_16x16x32_f16(a_h[0][kc], bm1, acc10, 0, 0, 0);
      acc11 = __builtin_amdgcn_mfma_f32_16x16x32_f16(a_h[1][kc], bm1, acc11, 0, 0, 0);
    }
    // C layout: col = lane&15 (code), row = (lane>>4)*4 + q
    {
      int code0 = (2 * p) * 16 + lc;
      int code1 = (2 * p + 1) * 16 + lc;
      float cn0 = cn_s[code0];
      float cn1 = cn_s[code1];
#pragma unroll
      for (int q = 0; q < 4; ++q) {
        float s00 = cn0 - 2.f * acc00[q];
        if (s00 < minv[0][q]) { minv[0][q] = s00; mini[0][q] = code0; }
        float s01 = cn0 - 2.f * acc01[q];
        if (s01 < minv[1][q]) { minv[1][q] = s01; mini[1][q] = code0; }
        float s10 = cn1 - 2.f * acc10[q];
        if (s10 < minv[0][q]) { minv[0][q] = s10; mini[0][q] = code1; }
        float s11 = cn1 - 2.f * acc11[q];
        if (s11 < minv[1][q]) { minv[1][q] = s11; mini[1][q] = code1; }
      }
    }
    __syncthreads();  // dbuf handshake: reads of buf[cur] done; stage of buf[cur^1] landed
  }
#undef STAGE

  // NOTE: tie-break correctness: within a lane, codes are visited in ascending
  // order and strict < keeps the first; code0 < code1 checked in order.

  // ---- cross-lane argmin over the 16 code-lanes of each row group ----
#pragma unroll
  for (int rt = 0; rt < RT; ++rt) {
#pragma unroll
    for (int q = 0; q < 4; ++q) {
      float v = minv[rt][q];
      int idx = mini[rt][q];
      for (int off = 1; off < 16; off <<= 1) {
        float ov = __shfl_xor(v, off);
        int oi = __shfl_xor(idx, off);
        if (ov < v || (ov == v && oi < idx)) { v = ov; idx = oi; }  // first-min wins
      }
      if (lc == 0) {
        int row = blockIdx.x * BMB + w * BMW + rt * 16 + lk * 4 + q;
        enc_int[row] = idx;
        enc_out[row] = (float)idx;
        atomicAdd(&hist[idx], 1);
      }
    }
  }
  __syncthreads();
  atomicAdd(&counts[tid], hist[tid]);
  atomicAdd(&counts[tid + 256], hist[tid + 256]);
}

// code gather -> code_ste output, per-block loss partials (NO same-address atomics)
__global__ __launch_bounds__(256) void gather_kernel(
    const float* __restrict__ z, const float* __restrict__ cb,
    const int* __restrict__ enc, float* __restrict__ code_out,
    float* __restrict__ loss_part) {
  const int per_block = (NROWS * (DIM / 4)) / GBLOCKS;  // 8192 float4s
  int base = blockIdx.x * per_block;
  float s = 0.f;
  for (int it = 0; it < per_block; it += 256) {
    int e4 = base + it + threadIdx.x;
    int row = e4 >> 6;        // 64 float4 per row
    int d4 = (e4 & 63) << 2;
    int k = enc[row];
    float4 zv = *(const float4*)&z[(size_t)e4 * 4];
    float4 cv = *(const float4*)&cb[(size_t)k * DIM + d4];
    *(float4*)&code_out[(size_t)e4 * 4] = cv;
    float dx = zv.x - cv.x, dy = zv.y - cv.y, dz = zv.z - cv.z, dw = zv.w - cv.w;
    s += dx * dx + dy * dy + dz * dz + dw * dw;
  }
  for (int off = 32; off > 0; off >>= 1) s += __shfl_down(s, off);
  __shared__ float p[4];
  int t = threadIdx.x;
  if ((t & 63) == 0) p[t >> 6] = s;
  __syncthreads();
  if (t == 0) loss_part[blockIdx.x] = (p[0] + p[1]) + (p[2] + p[3]);
}

// single block: n_new + exclusive prefix sum of counts -> cursor; loss reduce
__global__ __launch_bounds__(512) void scan_kernel(
    const int* __restrict__ counts, const float* __restrict__ n_i,
    float* __restrict__ n_new_out, int* __restrict__ cursor,
    const float* __restrict__ loss_part, float* __restrict__ loss_out) {
  __shared__ int sd[KCODES];
  int t = threadIdx.x;
  int c = counts[t];
  float nn = DECAYF * n_i[t] + OMDECAYF * (float)c;
  nn = (nn + EPSF) / (BATCHF + (float)KCODES * EPSF) * BATCHF;
  n_new_out[t] = nn;
  sd[t] = c;
  __syncthreads();
  for (int off = 1; off < KCODES; off <<= 1) {
    int v = (t >= off) ? sd[t - off] : 0;
    __syncthreads();
    sd[t] += v;
    __syncthreads();
  }
  cursor[t] = sd[t] - c;
  // loss reduction: 1024 partials over 512 threads
  float ls = loss_part[t] + loss_part[t + 512];
  for (int off = 32; off > 0; off >>= 1) ls += __shfl_down(ls, off);
  __shared__ float lp[8];
  if ((t & 63) == 0) lp[t >> 6] = ls;
  __syncthreads();
  if (t == 0) {
    float tot = 0.f;
#pragma unroll
    for (int i = 0; i < 8; ++i) tot += lp[i];
    loss_out[0] = 0.25f * tot / 33554432.0f;
  }
}

// LDS-aggregated counting-sort scatter: writes packed (code<<17)|row.
__global__ __launch_bounds__(256) void scatter_kernel(
    const int* __restrict__ enc, int* __restrict__ cursor,
    int* __restrict__ rowlist) {
  __shared__ int lcnt[KCODES];
  __shared__ int lbase[KCODES];
  int tid = threadIdx.x;
  int row = blockIdx.x * 256 + tid;
  lcnt[tid] = 0;
  lcnt[tid + 256] = 0;
  __syncthreads();
  int k = enc[row];
  int p = atomicAdd(&lcnt[k], 1);
  __syncthreads();
  int c0 = lcnt[tid];
  if (c0) lbase[tid] = atomicAdd(&cursor[tid], c0);
  int c1 = lcnt[tid + 256];
  if (c1) lbase[tid + 256] = atomicAdd(&cursor[tid + 256], c1);
  __syncthreads();
  rowlist[lbase[k] + p] = (k << 17) | row;
}

// Load-balanced segmented sum over sorted rowlist: 128 rows per block,
// run-length accumulate in registers, one atomicAdd per run per dim.
__global__ __launch_bounds__(256) void chunk_sum_kernel(
    const float* __restrict__ z, const int* __restrict__ rowlist,
    float* __restrict__ en_out) {
  __shared__ int rl[CHUNK];
  int tid = threadIdx.x;
  int d = tid;
  if (tid < CHUNK) rl[tid] = rowlist[blockIdx.x * CHUNK + tid];
  __syncthreads();
  int cur = rl[0] >> 17;
  float s = 0.f;
  for (int i = 0; i < CHUNK; i += 4) {
    int p0 = rl[i + 0], p1 = rl[i + 1], p2 = rl[i + 2], p3 = rl[i + 3];
    float v0 = z[(size_t)(p0 & ROWMASK) * DIM + d];
    float v1 = z[(size_t)(p1 & ROWMASK) * DIM + d];
    float v2 = z[(size_t)(p2 & ROWMASK) * DIM + d];
    float v3 = z[(size_t)(p3 & ROWMASK) * DIM + d];
    int k;
    k = p0 >> 17;
    if (k != cur) { atomicAdd(&en_out[(size_t)cur * DIM + d], OMDECAYF * s); s = 0.f; cur = k; }
    s += v0;
    k = p1 >> 17;
    if (k != cur) { atomicAdd(&en_out[(size_t)cur * DIM + d], OMDECAYF * s); s = 0.f; cur = k; }
    s += v1;
    k = p2 >> 17;
    if (k != cur) { atomicAdd(&en_out[(size_t)cur * DIM + d], OMDECAYF * s); s = 0.f; cur = k; }
    s += v2;
    k = p3 >> 17;
    if (k != cur) { atomicAdd(&en_out[(size_t)cur * DIM + d], OMDECAYF * s); s = 0.f; cur = k; }
    s += v3;
  }
  atomicAdd(&en_out[(size_t)cur * DIM + d], OMDECAYF * s);
}

// cbn = e_new / n_new
__global__ __launch_bounds__(256) void finalize_kernel(
    const float* __restrict__ en, const float* __restrict__ n_new,
    float* __restrict__ cbn_out) {
  int k = blockIdx.x;
  int d = threadIdx.x;
  size_t idx = (size_t)k * DIM + d;
  cbn_out[idx] = en[idx] / n_new[k];
}

extern "C" void kernel_launch(void* const* d_in, const int* in_sizes, int n_in,
                              void* d_out, int out_size, void* d_ws, size_t ws_size,
                              hipStream_t stream) {
  const float* z = (const float*)d_in[0];
  const float* cb = (const float*)d_in[1];
  const float* n_i = (const float*)d_in[2];
  const float* e_i = (const float*)d_in[3];

  float* out = (float*)d_out;
  float* out_code = out;                    // 33554432
  float* out_loss = out + 33554432;         // 1
  float* out_enc = out + 33554433;          // 131072
  float* out_cbn = out + 33685505;          // 131072
  float* out_nn = out + 33816577;           // 512
  float* out_en = out + 33817089;           // 131072

  char* ws = (char*)d_ws;
  float* cnorm = (float*)(ws + 0);
  int* counts = (int*)(ws + 2048);
  int* cursor = (int*)(ws + 6144);
  float* loss_part = (float*)(ws + 8192);
  int* enc_int = (int*)(ws + 12288);
  int* rowlist = (int*)(ws + 536576);

  // fp16 split planes of the codebook (fragment-ordered): scratch inside
  // out_code (512 KB), consumed by argmin before gather overwrites the region.
  unsigned short* planes = (unsigned short*)out_code;

  // zero counts (ws is poisoned 0xAA before each launch)
  hipMemsetAsync(ws + 2048, 0, 2048, stream);

  cnorm_kernel<<<KCODES, 256, 0, stream>>>(cb, e_i, cnorm, out_en, planes);
  argmin_kernel<<<NROWS / BMB, 256, 0, stream>>>(z, planes, cnorm, enc_int, out_enc, counts);
  gather_kernel<<<GBLOCKS, 256, 0, stream>>>(z, cb, enc_int, out_code, loss_part);
  scan_kernel<<<1, KCODES, 0, stream>>>(counts, n_i, out_nn, cursor, loss_part, out_loss);
  scatter_kernel<<<NROWS / 256, 256, 0, stream>>>(enc_int, cursor, rowlist);
  chunk_sum_kernel<<<NROWS / CHUNK, 256, 0, stream>>>(z, rowlist, out_en);
  finalize_kernel<<<KCODES, 256, 0, stream>>>(out_en, out_nn, out_cbn);
}